// Round 9
// baseline (22.881 us; speedup 1.0000x reference)
//
#include <hip/hip_runtime.h>
#include <hip/hip_bf16.h>

#define OUT_F 64
#define IN_F 64
#define M_PTS 20
#define BATCH 1024

#if __has_builtin(__builtin_amdgcn_exp2f)
#define EXP2(x) __builtin_amdgcn_exp2f(x)
#else
#define EXP2(x) exp2f(x)
#endif

// Tables (batch-independent, rebuilt every launch):
// g_cp[(o*20+m)*64+i] = u32 { bf16(B) << 16 | bf16(qmc) }
// g_aux[o*64+i]       = {s, s*z0, 2*s*delta, -(s*delta)^2}
// Recurrence: t_m = 2^{-(dx-m*g)^2}; t*=w, w*=v per m.
// edge_mean += qmc_m*t_m ; edge_var += B_m*t_m^2  (regularizer term dropped,
// <=~4e-5 abs; bf16 coeffs <=0.2% rel; r7 measured absmax 3.1e-2 vs 8.5e-2).
__device__ unsigned g_cp[OUT_F * M_PTS * IN_F];
__device__ float4   g_aux[OUT_F * IN_F];

static __device__ __forceinline__ unsigned f2bf(float f) {
    union { float f; unsigned u; } v; v.f = f;
    unsigned r = v.u + 0x7fffu + ((v.u >> 16) & 1u);   // rne
    return r >> 16;
}
static __device__ __forceinline__ float bflo(unsigned p) {
    union { unsigned u; float f; } v; v.u = p << 16; return v.f;
}
static __device__ __forceinline__ float bfhi(unsigned p) {
    union { unsigned u; float f; } v; v.u = p & 0xffff0000u; return v.f;
}

__global__ __launch_bounds__(256) void prep_kernel(
    const float* __restrict__ z, const float* __restrict__ q_mu,
    const float* __restrict__ q_log_var, const float* __restrict__ log_scale,
    const float* __restrict__ log_variance)
{
    int idx = blockIdx.x * 256 + threadIdx.x;   // = (o*20+m)*64 + i
    if (idx >= OUT_F * M_PTS * IN_F) return;
    int i  = idx & 63;
    int om = idx >> 6;
    int m  = om % M_PTS;
    int o  = om / M_PTS;
    int e  = o * IN_F + i;
    int ge = e * M_PTS + m;

    const float LOG2E = 1.4426950408889634f;
    float ell  = fmaxf(expf(log_scale[e]), 0.1f);
    float l2   = ell * ell;
    float sig2 = fmaxf(expf(log_variance[e]), 1e-5f);
    float den1 = l2 + 1e-6f;
    float den2 = l2 + 2e-6f;
    float c1   = sig2 * sqrtf(l2 / den1);
    float c2   = sig2 * sig2 * sqrtf(l2 / den2);
    float s    = sqrtf(0.5f * LOG2E / den1);

    float qm  = q_mu[ge];
    float qv  = fmaxf(expf(q_log_var[ge]), 1e-5f);
    float qmc = c1 * qm;
    float A   = c2 * (qm * qm + qv);
    float B   = A - qmc * qmc;

    g_cp[idx] = f2bf(qmc) | (f2bf(B) << 16);
    if (m == 0) {
        float z0  = z[ge];
        float z19 = z[e * M_PTS + (M_PTS - 1)];
        float delta = (z19 - z0) * (1.0f / (M_PTS - 1));
        float sd = s * delta;
        g_aux[e] = make_float4(s, s * z0, 2.0f * sd, -(sd * sd));
    }
}

// 8192 single-wave blocks: blk -> o = blk>>7 (128 consecutive blocks share o
// for coeff cache reuse), bc = blk&127 (8 batch rows each). lane = i.
// No LDS, no barriers: cross-lane i-reduction via select+shfl_xor fold.
#define BODY(P)                                                              \
    {                                                                        \
        float xb0 = xg[((2 * (P)) << 6) + lane];                             \
        float xb1 = xg[((2 * (P) + 1) << 6) + lane];                         \
        float dx0 = fmaf(s, xb0, -sz0);                                      \
        float dx1 = fmaf(s, xb1, -sz0);                                      \
        float t0  = EXP2(-(dx0 * dx0));                                      \
        float t1  = EXP2(-(dx1 * dx1));                                      \
        float w0  = EXP2(fminf(fmaf(cu1, dx0, cu0), 60.0f));                 \
        float w1  = EXP2(fminf(fmaf(cu1, dx1, cu0), 60.0f));                 \
        float em0 = 0.0f, em1 = 0.0f, ev0 = 0.0f, ev1 = 0.0f;                \
        _Pragma("unroll")                                                    \
        for (int m = 0; m < M_PTS; ++m) {                                    \
            unsigned c = cp[m];                                              \
            float qmc = bflo(c);                                             \
            float B   = bfhi(c);                                             \
            em0 = fmaf(qmc, t0, em0);                                        \
            em1 = fmaf(qmc, t1, em1);                                        \
            ev0 = fmaf(B, t0 * t0, ev0);                                     \
            ev1 = fmaf(B, t1 * t1, ev1);                                     \
            if (m < M_PTS - 1) { t0 *= w0; t1 *= w1; w0 *= v; w1 *= v; }     \
        }                                                                    \
        qa[2 * (P)]     = em0;                                               \
        qa[2 * (P) + 1] = em1;                                               \
        qa[8 + 2 * (P)] = fmaxf(ev0, 0.0f);                                  \
        qa[9 + 2 * (P)] = fmaxf(ev1, 0.0f);                                  \
    }

__global__ __launch_bounds__(64, 8) void gpkan_main(
    const float* __restrict__ x, float* __restrict__ out)
{
    const int blk  = blockIdx.x;
    const int o    = blk >> 7;
    const int bc   = blk & 127;
    const int lane = threadIdx.x;

    float4 aux = g_aux[(o << 6) + lane];
    const float s = aux.x, sz0 = aux.y, cu1 = aux.z, cu0 = aux.w;
    const float v = EXP2(cu0 + cu0);

    unsigned cp[M_PTS];
    #pragma unroll
    for (int m = 0; m < M_PTS; ++m)
        cp[m] = g_cp[((o * M_PTS + m) << 6) + lane];   // coalesced dword

    const float* __restrict__ xg = x + (bc << 9);      // 8 rows x 64

    float qa[16];                 // [0..7]=em rows, [8..15]=ev rows
    BODY(0) BODY(1) BODY(2) BODY(3)

    // Fold-reduce 16 values over 64 lanes.
    // Step k folds bit (5,4,3,2): keep/send split by that lane bit; after all
    // four steps each lane holds one value, row = b4*4+b3*2+b2, is_ev = b5.
    const bool s5 = (lane & 32) != 0;
    const bool s4 = (lane & 16) != 0;
    const bool s3 = (lane & 8) != 0;
    const bool s2 = (lane & 4) != 0;

    float k8[8];
    #pragma unroll
    for (int j = 0; j < 8; ++j) {
        float keep = s5 ? qa[j + 8] : qa[j];
        float send = s5 ? qa[j] : qa[j + 8];
        k8[j] = keep + __shfl_xor(send, 32);
    }
    float k4[4];
    #pragma unroll
    for (int j = 0; j < 4; ++j) {
        float keep = s4 ? k8[j + 4] : k8[j];
        float send = s4 ? k8[j] : k8[j + 4];
        k4[j] = keep + __shfl_xor(send, 16);
    }
    float k2[2];
    #pragma unroll
    for (int j = 0; j < 2; ++j) {
        float keep = s3 ? k4[j + 2] : k4[j];
        float send = s3 ? k4[j] : k4[j + 2];
        k2[j] = keep + __shfl_xor(send, 8);
    }
    float k1;
    {
        float keep = s2 ? k2[1] : k2[0];
        float send = s2 ? k2[0] : k2[1];
        k1 = keep + __shfl_xor(send, 4);
    }
    k1 += __shfl_xor(k1, 2);
    k1 += __shfl_xor(k1, 1);

    if ((lane & 3) == 0) {
        int row   = ((lane >> 4) & 1) * 4 + ((lane >> 3) & 1) * 2 + ((lane >> 2) & 1);
        int is_ev = (lane >> 5) & 1;
        int b     = (bc << 3) + row;
        out[is_ev * (BATCH * OUT_F) + b * OUT_F + o] = k1;
    }
}

extern "C" void kernel_launch(void* const* d_in, const int* in_sizes, int n_in,
                              void* d_out, int out_size, void* d_ws, size_t ws_size,
                              hipStream_t stream) {
    const float* x            = (const float*)d_in[0];
    const float* z            = (const float*)d_in[1];
    const float* q_mu         = (const float*)d_in[2];
    const float* q_log_var    = (const float*)d_in[3];
    const float* log_scale    = (const float*)d_in[4];
    const float* log_variance = (const float*)d_in[5];
    float* out = (float*)d_out;

    prep_kernel<<<(OUT_F * M_PTS * IN_F + 255) / 256, 256, 0, stream>>>(
        z, q_mu, q_log_var, log_scale, log_variance);
    gpkan_main<<<128 * OUT_F, 64, 0, stream>>>(x, out);
}

// Round 10
// 22.258 us; speedup vs baseline: 1.0280x; 1.0280x over previous
//
#include <hip/hip_runtime.h>
#include <hip/hip_bf16.h>

#define OUT_F 64
#define IN_F 64
#define M_PTS 20
#define BATCH 1024
#define NEPB (IN_F * M_PTS)        // 1280 coefficient entries per o

#if __has_builtin(__builtin_amdgcn_exp2f)
#define EXP2(x) __builtin_amdgcn_exp2f(x)
#else
#define EXP2(x) exp2f(x)
#endif
#define LOG2E 1.4426950408889634f

static __device__ __forceinline__ unsigned f2bf(float f) {
    union { float f; unsigned u; } v; v.f = f;
    unsigned r = v.u + 0x7fffu + ((v.u >> 16) & 1u);   // rne
    return r >> 16;
}
static __device__ __forceinline__ float bflo(unsigned p) {
    union { unsigned u; float f; } v; v.u = p << 16; return v.f;
}
static __device__ __forceinline__ float bfhi(unsigned p) {
    union { unsigned u; float f; } v; v.u = p & 0xffff0000u; return v.f;
}

// Hot-loop recurrence (validated r5-r9, absmax 3.1e-2 vs 8.5e-2 threshold):
// t_m = 2^{-(dx-m*g)^2}; t*=w, w*=v per m; edge_mean += qmc_m*t_m,
// edge_var += B_m*t_m^2 (B>0 provably; regularizer term dropped <=4e-5 abs;
// bf16 coeffs <=0.2% rel).
#define BODY(P)                                                              \
    {                                                                        \
        float xb0 = xg[((2 * (P)) << 6) + lane];                             \
        float xb1 = xg[((2 * (P) + 1) << 6) + lane];                         \
        float dx0 = fmaf(s, xb0, -sz0);                                      \
        float dx1 = fmaf(s, xb1, -sz0);                                      \
        float t0  = EXP2(-(dx0 * dx0));                                      \
        float t1  = EXP2(-(dx1 * dx1));                                      \
        float w0  = EXP2(fminf(fmaf(cu1, dx0, cu0), 60.0f));                 \
        float w1  = EXP2(fminf(fmaf(cu1, dx1, cu0), 60.0f));                 \
        float em0 = 0.0f, em1 = 0.0f, ev0 = 0.0f, ev1 = 0.0f;                \
        _Pragma("unroll")                                                    \
        for (int m = 0; m < M_PTS; ++m) {                                    \
            unsigned c = cp[m];                                              \
            float qmc = bflo(c);                                             \
            float B   = bfhi(c);                                             \
            em0 = fmaf(qmc, t0, em0);                                        \
            em1 = fmaf(qmc, t1, em1);                                        \
            ev0 = fmaf(B, t0 * t0, ev0);                                     \
            ev1 = fmaf(B, t1 * t1, ev1);                                     \
            if (m < M_PTS - 1) { t0 *= w0; t1 *= w1; w0 *= v; w1 *= v; }     \
        }                                                                    \
        qa[2 * (P)]     = em0;                                               \
        qa[2 * (P) + 1] = em1;                                               \
        qa[8 + 2 * (P)] = fmaxf(ev0, 0.0f);                                  \
        qa[9 + 2 * (P)] = fmaxf(ev1, 0.0f);                                  \
    }

// Single fused kernel. 1024 blocks x 512 threads (8 waves); block ->
// (o = blk>>4, bc = blk&15, 64 batch rows). Phase 1: block computes its o's
// coefficients into LDS (exp2-based, coalesced loads). Phase 2: wave wv
// handles 8 rows with the r9 register-resident hot loop + shfl-fold.
__global__ __launch_bounds__(512, 8) void gpkan_fused(
    const float* __restrict__ x, const float* __restrict__ z,
    const float* __restrict__ q_mu, const float* __restrict__ q_log_var,
    const float* __restrict__ log_scale, const float* __restrict__ log_variance,
    float* __restrict__ out)
{
    __shared__ unsigned c_lds[NEPB];       // [m][i] = m*64 + i
    __shared__ float4   aux_lds[IN_F];     // {s, s*z0, 2*s*d, -(s*d)^2}

    const int blk = blockIdx.x;
    const int o   = blk >> 4;
    const int bc  = blk & 15;
    const int tid = threadIdx.x;

    // ---- phase 1: coefficients (<=3 entries per thread, coalesced) ----
    const int base = o * NEPB;
    #pragma unroll
    for (int kk = 0; kk < 3; ++kk) {
        int idx = tid + (kk << 9);          // 0..1535, guard at 1280
        if (idx < NEPB) {
            int i = idx / M_PTS;            // const divisor -> magic mul
            int m = idx - i * M_PTS;
            int e = (o << 6) + i;

            float ell  = fmaxf(EXP2(log_scale[e] * LOG2E), 0.1f);
            float l2   = ell * ell;
            float sig2 = fmaxf(EXP2(log_variance[e] * LOG2E), 1e-5f);
            float den1 = l2 + 1e-6f;
            float den2 = l2 + 2e-6f;
            float c1   = sig2 * sqrtf(l2 / den1);
            float c2   = sig2 * sig2 * sqrtf(l2 / den2);

            float qm  = q_mu[base + idx];
            float qv  = fmaxf(EXP2(q_log_var[base + idx] * LOG2E), 1e-5f);
            float qmc = c1 * qm;
            float A   = c2 * (qm * qm + qv);
            float B   = A - qmc * qmc;

            c_lds[(m << 6) + i] = f2bf(qmc) | (f2bf(B) << 16);

            if (m == 0) {
                float sE    = sqrtf(0.5f * LOG2E / den1);
                float z0    = z[base + idx];
                float z19   = z[base + idx + (M_PTS - 1)];
                float delta = (z19 - z0) * (1.0f / (M_PTS - 1));
                float sd    = sE * delta;
                aux_lds[i]  = make_float4(sE, sE * z0, 2.0f * sd, -(sd * sd));
            }
        }
    }
    __syncthreads();

    // ---- phase 2: hot loop (8 rows per wave) ----
    const int lane = tid & 63;
    const int wv   = __builtin_amdgcn_readfirstlane(tid >> 6);

    float4 aux = aux_lds[lane];
    const float s = aux.x, sz0 = aux.y, cu1 = aux.z, cu0 = aux.w;
    const float v = EXP2(cu0 + cu0);

    unsigned cp[M_PTS];
    #pragma unroll
    for (int m = 0; m < M_PTS; ++m)
        cp[m] = c_lds[(m << 6) + lane];     // 2-way bank alias = free

    const int r0 = (bc << 6) + (wv << 3);   // first of this wave's 8 rows
    const float* __restrict__ xg = x + r0 * IN_F;

    float qa[16];                  // [0..7]=em rows, [8..15]=ev rows
    BODY(0) BODY(1) BODY(2) BODY(3)

    // Fold-reduce 16 values over 64 lanes (verified r9).
    const bool s5 = (lane & 32) != 0;
    const bool s4 = (lane & 16) != 0;
    const bool s3 = (lane & 8) != 0;
    const bool s2 = (lane & 4) != 0;

    float k8[8];
    #pragma unroll
    for (int j = 0; j < 8; ++j) {
        float keep = s5 ? qa[j + 8] : qa[j];
        float send = s5 ? qa[j] : qa[j + 8];
        k8[j] = keep + __shfl_xor(send, 32);
    }
    float k4[4];
    #pragma unroll
    for (int j = 0; j < 4; ++j) {
        float keep = s4 ? k8[j + 4] : k8[j];
        float send = s4 ? k8[j] : k8[j + 4];
        k4[j] = keep + __shfl_xor(send, 16);
    }
    float k2[2];
    #pragma unroll
    for (int j = 0; j < 2; ++j) {
        float keep = s3 ? k4[j + 2] : k4[j];
        float send = s3 ? k4[j] : k4[j + 2];
        k2[j] = keep + __shfl_xor(send, 8);
    }
    float k1;
    {
        float keep = s2 ? k2[1] : k2[0];
        float send = s2 ? k2[0] : k2[1];
        k1 = keep + __shfl_xor(send, 4);
    }
    k1 += __shfl_xor(k1, 2);
    k1 += __shfl_xor(k1, 1);

    if ((lane & 3) == 0) {
        int row   = ((lane >> 4) & 1) * 4 + ((lane >> 3) & 1) * 2 + ((lane >> 2) & 1);
        int is_ev = (lane >> 5) & 1;
        int b     = r0 + row;
        out[is_ev * (BATCH * OUT_F) + b * OUT_F + o] = k1;
    }
}

extern "C" void kernel_launch(void* const* d_in, const int* in_sizes, int n_in,
                              void* d_out, int out_size, void* d_ws, size_t ws_size,
                              hipStream_t stream) {
    const float* x            = (const float*)d_in[0];
    const float* z            = (const float*)d_in[1];
    const float* q_mu         = (const float*)d_in[2];
    const float* q_log_var    = (const float*)d_in[3];
    const float* log_scale    = (const float*)d_in[4];
    const float* log_variance = (const float*)d_in[5];
    float* out = (float*)d_out;

    gpkan_fused<<<OUT_F * 16, 512, 0, stream>>>(
        x, z, q_mu, q_log_var, log_scale, log_variance, out);
}